// Round 2
// baseline (1361.633 us; speedup 1.0000x reference)
//
#include <hip/hip_runtime.h>
#include <hip/hip_bf16.h>
#include <math.h>

// ---------------------------------------------------------------------------
// Round 1: fit workspace in 191.4 MB (R0 failure = ws_size guard early-return:
// absmax was exactly |bf16(-1e9) - 0| i.e. untouched output buffer).
// B=256 S=360 D=256 H=4 DK=64 DFF=2048 PREFIX=340 PAD=799 NPAIR=91 M=92160
// ws layout (bytes, all bf16 unless noted):
//   x    [M][256]                @ 0            47,185,920   (residual stream)
//   xn   [M][256]                @ 47,185,920   47,185,920   (LN1 out; later LN2 out)
//   R region                     @ 94,371,840   94,371,840
//     attn phase (per half, 128 batches):
//       qh  [128,H,S,DK]  @R+0          23,592,960
//       kh  [128,H,S,DK]  @R+23,592,960 23,592,960
//       vth [128,H,DK,S]  @R+47,185,920 23,592,960
//       ctxh[46080][256]  @R+70,778,880 23,592,960  (vth tail-read pads into it, x0)
//     ffn phase: h [M][512] @R+0  94,371,840
//   wT  (wq,wk,wv,wo,w1,w2 transposed bf16) @ 188,743,680  2,621,440
// total 191,365,120 B
// ---------------------------------------------------------------------------

using bf16 = __hip_bfloat16;
typedef __attribute__((ext_vector_type(8))) short frag8;
typedef __attribute__((ext_vector_type(4))) float f32x4;

static __device__ __forceinline__ float wave_sum64(float v){
  #pragma unroll
  for (int o = 32; o >= 1; o >>= 1) v += __shfl_xor(v, o, 64);
  return v;
}

// dst[n*K+k] = (bf16) src[k*N+n]
__global__ __launch_bounds__(256) void cvt_transpose(bf16* __restrict__ dst,
                                                     const float* __restrict__ src,
                                                     int K, int N){
  int idx = blockIdx.x * 256 + threadIdx.x;
  if (idx >= K * N) return;
  int n = idx / K, k = idx - n * K;
  dst[idx] = __float2bfloat16(src[(size_t)k * N + n]);
}

// embed + PE + scale -> x (bf16), LN1 -> xn (bf16). one wave/row, grid 23040.
__global__ __launch_bounds__(256) void embed_ln1(
    const int* __restrict__ src, const float* __restrict__ emb,
    const float* __restrict__ na, const float* __restrict__ nb,
    bf16* __restrict__ x, bf16* __restrict__ xn)
{
  int row  = blockIdx.x * 4 + (threadIdx.x >> 6);
  int lane = threadIdx.x & 63;
  int s = row % 360;
  int tok = src[row];
  float4 v = *(const float4*)(emb + (size_t)tok * 256 + lane * 4);
  float vv[4] = {v.x, v.y, v.z, v.w};
  if (s < 340){
    const float C = (-2.0f / 256.0f) * 13.287712379549449f;  // -2/D * log2(10000)
    #pragma unroll
    for (int t = 0; t < 4; t++){
      int c = lane * 4 + t;
      float ang = (float)s * exp2f(C * (float)c);
      float pe = (c & 1) ? cosf(ang) : sinf(ang);
      vv[t] = 16.0f * vv[t] + pe;
    }
  }
  float sum = wave_sum64(vv[0] + vv[1] + vv[2] + vv[3]);
  float mu = sum * (1.0f / 256.0f);
  float d0 = vv[0]-mu, d1 = vv[1]-mu, d2 = vv[2]-mu, d3 = vv[3]-mu;
  float sq = wave_sum64(d0*d0 + d1*d1 + d2*d2 + d3*d3);
  float inv = 1.0f / (sqrtf(sq * (1.0f / 255.0f)) + 1e-6f);
  bf16 xo[4] = { __float2bfloat16(vv[0]), __float2bfloat16(vv[1]),
                 __float2bfloat16(vv[2]), __float2bfloat16(vv[3]) };
  *(uint2*)(x + (size_t)row * 256 + lane * 4) = *(uint2*)xo;
  float4 a4 = *(const float4*)(na + lane * 4);
  float4 b4 = *(const float4*)(nb + lane * 4);
  bf16 o4[4] = { __float2bfloat16(a4.x * d0 * inv + b4.x),
                 __float2bfloat16(a4.y * d1 * inv + b4.y),
                 __float2bfloat16(a4.z * d2 * inv + b4.z),
                 __float2bfloat16(a4.w * d3 * inv + b4.w) };
  *(uint2*)(xn + (size_t)row * 256 + lane * 4) = *(uint2*)o4;
}

// LN over bf16 x -> bf16 xn. one wave per row. grid 23040.
__global__ __launch_bounds__(256) void ln_k(
    const bf16* __restrict__ x, const float* __restrict__ na,
    const float* __restrict__ nb, bf16* __restrict__ xn)
{
  int row  = blockIdx.x * 4 + (threadIdx.x >> 6);
  int lane = threadIdx.x & 63;
  uint2 raw = *(const uint2*)(x + (size_t)row * 256 + lane * 4);
  bf16* xr = (bf16*)&raw;
  float v0 = __bfloat162float(xr[0]), v1 = __bfloat162float(xr[1]);
  float v2 = __bfloat162float(xr[2]), v3 = __bfloat162float(xr[3]);
  float sum = wave_sum64(v0 + v1 + v2 + v3);
  float mu = sum * (1.0f / 256.0f);
  float d0 = v0-mu, d1 = v1-mu, d2 = v2-mu, d3 = v3-mu;
  float sq = wave_sum64(d0*d0 + d1*d1 + d2*d2 + d3*d3);
  float inv = 1.0f / (sqrtf(sq * (1.0f / 255.0f)) + 1e-6f);
  float4 a4 = *(const float4*)(na + lane * 4);
  float4 b4 = *(const float4*)(nb + lane * 4);
  bf16 o4[4] = { __float2bfloat16(a4.x * d0 * inv + b4.x),
                 __float2bfloat16(a4.y * d1 * inv + b4.y),
                 __float2bfloat16(a4.z * d2 * inv + b4.z),
                 __float2bfloat16(a4.w * d3 * inv + b4.w) };
  *(uint2*)(xn + (size_t)row * 256 + lane * 4) = *(uint2*)o4;
}

// C = A[M][K](bf16) @ Bt[N][K]^T(bf16) + bias, 128x128 tile, BK=32, 4 waves.
// Rows are LOCAL to the passed pointers (halves handled by pointer offsets).
// MODE 0: q/k layout  out[b][h][s][dk] bf16   (b = m/360 local)
// MODE 1: v  layout   out[b][h][dk][s] bf16
// MODE 2: relu, bf16 row-major [M][N]
// MODE 3: bf16 residual in-place: xres[m*256+n] += acc (+bias)
template<int MODE>
__global__ __launch_bounds__(256) void gemm_bt(
    const bf16* __restrict__ A, int lda,
    const bf16* __restrict__ Bt, int ldb,
    const float* __restrict__ bias,
    bf16* __restrict__ outb, bf16* __restrict__ xres,
    int N, int K)
{
  __shared__ bf16 As[128][40];
  __shared__ bf16 Bs[128][40];
  int m0 = blockIdx.x * 128, n0 = blockIdx.y * 128;
  int tid = threadIdx.x;
  int wave = tid >> 6, lane = tid & 63;
  int wm = (wave >> 1) * 64, wn = (wave & 1) * 64;
  int r = lane & 15, qd = lane >> 4;

  f32x4 zero4 = {0.f, 0.f, 0.f, 0.f};
  f32x4 acc[4][4];
  #pragma unroll
  for (int mt = 0; mt < 4; mt++)
    #pragma unroll
    for (int nt = 0; nt < 4; nt++) acc[mt][nt] = zero4;

  for (int k0 = 0; k0 < K; k0 += 32){
    for (int c = tid; c < 512; c += 256){
      int row = c >> 2, cc = c & 3;
      *(uint4*)(&As[row][cc * 8]) = *(const uint4*)(A  + (size_t)(m0 + row) * lda + k0 + cc * 8);
      *(uint4*)(&Bs[row][cc * 8]) = *(const uint4*)(Bt + (size_t)(n0 + row) * ldb + k0 + cc * 8);
    }
    __syncthreads();
    frag8 af[4], bfr[4];
    #pragma unroll
    for (int t = 0; t < 4; t++){
      af[t]  = *(const frag8*)(&As[wm + t * 16 + r][qd * 8]);
      bfr[t] = *(const frag8*)(&Bs[wn + t * 16 + r][qd * 8]);
    }
    #pragma unroll
    for (int mt = 0; mt < 4; mt++)
      #pragma unroll
      for (int nt = 0; nt < 4; nt++)
        acc[mt][nt] = __builtin_amdgcn_mfma_f32_16x16x32_bf16(af[mt], bfr[nt], acc[mt][nt], 0, 0, 0);
    __syncthreads();
  }

  #pragma unroll
  for (int mt = 0; mt < 4; mt++)
    #pragma unroll
    for (int nt = 0; nt < 4; nt++)
      #pragma unroll
      for (int i = 0; i < 4; i++){
        int m = m0 + wm + mt * 16 + qd * 4 + i;
        int n = n0 + wn + nt * 16 + r;
        float v = acc[mt][nt][i];
        if (bias) v += bias[n];
        if (MODE == 0){
          int b = m / 360, s = m - b * 360;
          int h = n >> 6, dk = n & 63;
          outb[(((size_t)(b * 4 + h) * 360 + s) << 6) + dk] = __float2bfloat16(v);
        } else if (MODE == 1){
          int b = m / 360, s = m - b * 360;
          int h = n >> 6, dk = n & 63;
          outb[((size_t)((b * 4 + h) * 64 + dk)) * 360 + s] = __float2bfloat16(v);
        } else if (MODE == 2){
          v = fmaxf(v, 0.0f);
          outb[(size_t)m * N + n] = __float2bfloat16(v);
        } else {
          size_t o = (size_t)m * 256 + n;
          xres[o] = __float2bfloat16(__bfloat162float(xres[o]) + v);
        }
      }
}

// attention on one half (128 batches): one block per (b_local,h), 4 waves.
// scores in registers, softmax via 16-lane shuffles, P->LDS->A-frag, PV mfma.
__global__ __launch_bounds__(256) void attn(
    const bf16* __restrict__ q, const bf16* __restrict__ kk, const bf16* __restrict__ vt,
    const int* __restrict__ src, bf16* __restrict__ ctx)
{
  __shared__ bf16 P[4][16][392];
  int bh = blockIdx.x;            // 0..511 local
  int b = bh >> 2, h = bh & 3;    // b local 0..127
  const bf16* qb = q  + (size_t)bh * 360 * 64;
  const bf16* kb = kk + (size_t)bh * 360 * 64;
  const bf16* vb = vt + (size_t)bh * 64 * 360;
  int wave = threadIdx.x >> 6, lane = threadIdx.x & 63;
  int r = lane & 15, qd = lane >> 4;
  bf16 (* __restrict__ Pw)[392] = P[wave];
  const int* srow = src + b * 360;

  for (int qt = wave; qt < 23; qt += 4){
    int qrow = qt * 16 + r; if (qrow > 359) qrow = 359;
    frag8 qa0 = *(const frag8*)(qb + qrow * 64 + qd * 8);
    frag8 qa1 = *(const frag8*)(qb + qrow * 64 + 32 + qd * 8);

    f32x4 sc[23];
    #pragma unroll
    for (int kt = 0; kt < 23; kt++){
      int krow = kt * 16 + r; if (krow > 359) krow = 359;
      frag8 kb0 = *(const frag8*)(kb + krow * 64 + qd * 8);
      frag8 kb1 = *(const frag8*)(kb + krow * 64 + 32 + qd * 8);
      f32x4 z = {0.f, 0.f, 0.f, 0.f};
      z = __builtin_amdgcn_mfma_f32_16x16x32_bf16(qa0, kb0, z, 0, 0, 0);
      z = __builtin_amdgcn_mfma_f32_16x16x32_bf16(qa1, kb1, z, 0, 0, 0);
      sc[kt] = z;
    }

    // reference masks PAD *queries* (uniform softmax on those rows), keys unmasked
    bool qpad[4];
    #pragma unroll
    for (int i = 0; i < 4; i++){
      int qg = qt * 16 + qd * 4 + i;
      qpad[i] = (qg < 360) && (srow[qg] == 799);
    }
    float mx[4] = {-INFINITY, -INFINITY, -INFINITY, -INFINITY};
    #pragma unroll
    for (int kt = 0; kt < 23; kt++){
      int key = kt * 16 + r;
      #pragma unroll
      for (int i = 0; i < 4; i++){
        float s = sc[kt][i] * 0.125f;
        if (qpad[i]) s = -1.0e9f;
        if (key >= 360) s = -INFINITY;
        sc[kt][i] = s;
        mx[i] = fmaxf(mx[i], s);
      }
    }
    #pragma unroll
    for (int i = 0; i < 4; i++){
      #pragma unroll
      for (int o = 1; o < 16; o <<= 1) mx[i] = fmaxf(mx[i], __shfl_xor(mx[i], o, 64));
    }
    float sm[4] = {0.f, 0.f, 0.f, 0.f};
    #pragma unroll
    for (int kt = 0; kt < 23; kt++)
      #pragma unroll
      for (int i = 0; i < 4; i++){
        float p = __expf(sc[kt][i] - mx[i]);
        sc[kt][i] = p;
        sm[i] += p;
      }
    #pragma unroll
    for (int i = 0; i < 4; i++){
      #pragma unroll
      for (int o = 1; o < 16; o <<= 1) sm[i] += __shfl_xor(sm[i], o, 64);
    }

    // P -> LDS (C-layout positions), zero pad cols 368..383
    #pragma unroll
    for (int kt = 0; kt < 23; kt++)
      #pragma unroll
      for (int i = 0; i < 4; i++)
        Pw[qd * 4 + i][kt * 16 + r] = __float2bfloat16(sc[kt][i]);
    #pragma unroll
    for (int i = 0; i < 4; i++)
      Pw[qd * 4 + i][368 + r] = __float2bfloat16(0.0f);
    asm volatile("s_waitcnt lgkmcnt(0)" ::: "memory");

    // PV  (keys 360..383 contribute 0 via zeroed P; vt tail reads land in pad)
    f32x4 accO[4];
    #pragma unroll
    for (int dt = 0; dt < 4; dt++) accO[dt] = (f32x4){0.f, 0.f, 0.f, 0.f};
    #pragma unroll
    for (int kc = 0; kc < 12; kc++){
      frag8 pa = *(const frag8*)(&Pw[r][kc * 32 + qd * 8]);
      #pragma unroll
      for (int dt = 0; dt < 4; dt++){
        frag8 vf = *(const frag8*)(vb + (size_t)(dt * 16 + r) * 360 + kc * 32 + qd * 8);
        accO[dt] = __builtin_amdgcn_mfma_f32_16x16x32_bf16(pa, vf, accO[dt], 0, 0, 0);
      }
    }
    float invs[4];
    #pragma unroll
    for (int i = 0; i < 4; i++) invs[i] = 1.0f / sm[i];
    #pragma unroll
    for (int dt = 0; dt < 4; dt++)
      #pragma unroll
      for (int i = 0; i < 4; i++){
        int m = qt * 16 + qd * 4 + i;
        if (m < 360)
          ctx[((size_t)(b * 360 + m)) * 256 + h * 64 + dt * 16 + r] =
              __float2bfloat16(accO[dt][i] * invs[i]);
      }
    asm volatile("s_waitcnt lgkmcnt(0)" ::: "memory");  // WAR before next tile's P writes
  }
}

// head: one wave per (b, pair). 5824 blocks x 4 waves = 23296 = 256*91.
__global__ __launch_bounds__(256) void head_k(
    const bf16* __restrict__ x, const int* __restrict__ src,
    const float* __restrict__ wl, const float* __restrict__ bl,
    float* __restrict__ out)
{
  int widx = blockIdx.x * 4 + (threadIdx.x >> 6);
  if (widx >= 23296) return;
  int lane = threadIdx.x & 63;
  int b = widx / 91, p = widx - b * 91;

  int i = 0, rem = p;
  while (rem >= 13 - i){ rem -= 13 - i; i++; }
  int j = i + 1 + rem;
  int base = 12 * i - (i * (i - 1)) / 2;
  int pe = base + (j - i) - 1;
  int eb = 28 + 2 * pe;

  int g = lane >> 3, sub = lane & 7;
  int idxg;
  if (g == 0) idxg = 2 * i;
  else if (g == 1) idxg = 2 * i + 1;
  else if (g == 2) idxg = 2 * j;
  else if (g == 3) idxg = 2 * j + 1;
  else idxg = eb + (g - 4);
  bool zm = !(g >= 4 && j == 13);

  float a0 = 0.f, a1 = 0.f, a2 = 0.f;
  if (zm){
    const bf16* xr = x + ((size_t)b * 360 + idxg) * 256 + sub * 32;
    const float* wr = wl + (size_t)(g * 256 + sub * 32) * 3;
    #pragma unroll
    for (int t = 0; t < 32; t++){
      float f = __bfloat162float(xr[t]);
      a0 += f * wr[t * 3 + 0];
      a1 += f * wr[t * 3 + 1];
      a2 += f * wr[t * 3 + 2];
    }
  }
  #pragma unroll
  for (int o = 1; o < 64; o <<= 1){
    a0 += __shfl_xor(a0, o, 64);
    a1 += __shfl_xor(a1, o, 64);
    a2 += __shfl_xor(a2, o, 64);
  }
  if (lane == 0){
    const int* sr = src + b * 360;
    int ti = sr[2 * i], ai = sr[2 * i + 1], tj = sr[2 * j], aj = sr[2 * j + 1];
    bool c1 = (ai == 2) || (aj == 2);
    bool c2 = (tj == 1) || (ai == 1) || (aj == 1);
    bool c3 = (ti == 799) || (tj == 799) || (ai == 0) || (aj == 0);
    bool c4 = false;
    if (j < 13){
      int es = 28 + 4 * pe;
      c4 = (sr[es] == 1) || (sr[es + 1] == 1) || (sr[es + 2] == 1) || (sr[es + 3] == 1);
    }
    bool m1 = c3 || c4, m2 = m1 || c2, m3 = m2 || c1;
    float* op = out + ((size_t)b * 91 + p) * 3;
    op[0] = m1 ? -1.0e9f : (a0 + bl[0]);
    op[1] = m2 ? -1.0e9f : (a1 + bl[1]);
    op[2] = m3 ? -1.0e9f : (a2 + bl[2]);
  }
}

extern "C" void kernel_launch(void* const* d_in, const int* in_sizes, int n_in,
                              void* d_out, int out_size, void* d_ws, size_t ws_size,
                              hipStream_t stream)
{
  const int*   src = (const int*)  d_in[0];
  const float* emb = (const float*)d_in[1];
  const float* wq  = (const float*)d_in[2];  const float* bq = (const float*)d_in[3];
  const float* wk  = (const float*)d_in[4];  const float* bk = (const float*)d_in[5];
  const float* wv  = (const float*)d_in[6];  const float* bv = (const float*)d_in[7];
  const float* wo  = (const float*)d_in[8];  const float* bo = (const float*)d_in[9];
  const float* n1a = (const float*)d_in[10]; const float* n1b = (const float*)d_in[11];
  const float* n2a = (const float*)d_in[12]; const float* n2b = (const float*)d_in[13];
  const float* w1  = (const float*)d_in[14]; const float* b1 = (const float*)d_in[15];
  const float* w2  = (const float*)d_in[16]; const float* b2 = (const float*)d_in[17];
  const float* wl  = (const float*)d_in[18]; const float* bl = (const float*)d_in[19];
  float* out = (float*)d_out;

  if (ws_size < 191365120ull) return;  // ws too small -> distinct signature (all-zero out)

  char* ws = (char*)d_ws;
  bf16* x   = (bf16*)(ws);                    // [92160][256]
  bf16* xn  = (bf16*)(ws + 47185920ull);      // [92160][256]
  char* R   = ws + 94371840ull;
  bf16* qh   = (bf16*)(R);                    // [128*4][360][64]
  bf16* kh   = (bf16*)(R + 23592960ull);
  bf16* vth  = (bf16*)(R + 47185920ull);      // [128*4][64][360]
  bf16* ctxh = (bf16*)(R + 70778880ull);      // [46080][256]
  bf16* hbuf = (bf16*)(R);                    // ffn phase: [92160][512]
  bf16* wT   = (bf16*)(ws + 188743680ull);
  bf16* wqT = wT;
  bf16* wkT = wT + 65536;
  bf16* wvT = wT + 131072;
  bf16* woT = wT + 196608;
  bf16* w1T = wT + 262144;       // [2048][256]
  bf16* w2T = w1T + 524288;      // [256][2048]

  cvt_transpose<<<256, 256, 0, stream>>>(wqT, wq, 256, 256);
  cvt_transpose<<<256, 256, 0, stream>>>(wkT, wk, 256, 256);
  cvt_transpose<<<256, 256, 0, stream>>>(wvT, wv, 256, 256);
  cvt_transpose<<<256, 256, 0, stream>>>(woT, wo, 256, 256);
  cvt_transpose<<<2048, 256, 0, stream>>>(w1T, w1, 256, 2048);
  cvt_transpose<<<2048, 256, 0, stream>>>(w2T, w2, 2048, 256);

  embed_ln1<<<23040, 256, 0, stream>>>(src, emb, n1a, n1b, x, xn);

  dim3 gh(360, 2), g2(720, 2), g4(720, 4);
  for (int half = 0; half < 2; half++){
    size_t ro = (size_t)half * 46080;          // row offset
    const bf16* xnh = xn + ro * 256;
    gemm_bt<0><<<gh, 256, 0, stream>>>(xnh, 256, wqT, 256, bq, qh,  nullptr, 256, 256);
    gemm_bt<0><<<gh, 256, 0, stream>>>(xnh, 256, wkT, 256, bk, kh,  nullptr, 256, 256);
    gemm_bt<1><<<gh, 256, 0, stream>>>(xnh, 256, wvT, 256, bv, vth, nullptr, 256, 256);
    attn<<<512, 256, 0, stream>>>(qh, kh, vth, src + ro, ctxh);
    gemm_bt<3><<<gh, 256, 0, stream>>>(ctxh, 256, woT, 256, bo, nullptr, x + ro * 256, 256, 256);
  }

  ln_k<<<23040, 256, 0, stream>>>(x, n2a, n2b, xn);

  for (int c = 0; c < 4; c++){
    gemm_bt<2><<<g4, 256, 0, stream>>>(xn, 256, w1T + (size_t)c * 512 * 256, 256,
                                       b1 + c * 512, hbuf, nullptr, 512, 256);
    gemm_bt<3><<<g2, 256, 0, stream>>>(hbuf, 512, w2T + (size_t)c * 512, 2048,
                                       (c == 0 ? b2 : nullptr), nullptr, x, 256, 512);
  }

  head_k<<<5824, 256, 0, stream>>>(x, src, wl, bl, out);
}

// Round 3
// 1207.925 us; speedup vs baseline: 1.1272x; 1.1272x over previous
//
#include <hip/hip_runtime.h>
#include <hip/hip_bf16.h>
#include <math.h>

// ---------------------------------------------------------------------------
// Round 2: (1) streaming 2-pass attention (no big LDS, no sc[23] regs, 6x blocks)
//          (2) gemm_bt with global_load_lds 16B staging (m97 pattern)
//          (3) QKV merged into one N=768 GEMM per half
// ws layout unchanged from R1 (191,365,120 B) — R1 passed so ws is big enough.
// ---------------------------------------------------------------------------

using bf16 = __hip_bfloat16;
typedef __attribute__((ext_vector_type(8))) short frag8;
typedef __attribute__((ext_vector_type(4))) float f32x4;

static __device__ __forceinline__ float wave_sum64(float v){
  #pragma unroll
  for (int o = 32; o >= 1; o >>= 1) v += __shfl_xor(v, o, 64);
  return v;
}

static __device__ __forceinline__ void gl_lds16(const bf16* g, bf16* l){
  __builtin_amdgcn_global_load_lds((const __attribute__((address_space(1))) void*)g,
                                   (__attribute__((address_space(3))) void*)l, 16, 0, 0);
}

static __device__ __forceinline__ unsigned pack2(float a, float b){
  union { bf16 h[2]; unsigned u; } u;
  u.h[0] = __float2bfloat16(a); u.h[1] = __float2bfloat16(b);
  return u.u;
}

// dst[n*K+k] = (bf16) src[k*N+n]
__global__ __launch_bounds__(256) void cvt_transpose(bf16* __restrict__ dst,
                                                     const float* __restrict__ src,
                                                     int K, int N){
  int idx = blockIdx.x * 256 + threadIdx.x;
  if (idx >= K * N) return;
  int n = idx / K, k = idx - n * K;
  dst[idx] = __float2bfloat16(src[(size_t)k * N + n]);
}

// embed + PE + scale -> x (bf16), LN1 -> xn (bf16). one wave/row, grid 23040.
__global__ __launch_bounds__(256) void embed_ln1(
    const int* __restrict__ src, const float* __restrict__ emb,
    const float* __restrict__ na, const float* __restrict__ nb,
    bf16* __restrict__ x, bf16* __restrict__ xn)
{
  int row  = blockIdx.x * 4 + (threadIdx.x >> 6);
  int lane = threadIdx.x & 63;
  int s = row % 360;
  int tok = src[row];
  float4 v = *(const float4*)(emb + (size_t)tok * 256 + lane * 4);
  float vv[4] = {v.x, v.y, v.z, v.w};
  if (s < 340){
    const float C = (-2.0f / 256.0f) * 13.287712379549449f;  // -2/D * log2(10000)
    #pragma unroll
    for (int t = 0; t < 4; t++){
      int c = lane * 4 + t;
      float ang = (float)s * exp2f(C * (float)c);
      float pe = (c & 1) ? cosf(ang) : sinf(ang);
      vv[t] = 16.0f * vv[t] + pe;
    }
  }
  float sum = wave_sum64(vv[0] + vv[1] + vv[2] + vv[3]);
  float mu = sum * (1.0f / 256.0f);
  float d0 = vv[0]-mu, d1 = vv[1]-mu, d2 = vv[2]-mu, d3 = vv[3]-mu;
  float sq = wave_sum64(d0*d0 + d1*d1 + d2*d2 + d3*d3);
  float inv = 1.0f / (sqrtf(sq * (1.0f / 255.0f)) + 1e-6f);
  bf16 xo[4] = { __float2bfloat16(vv[0]), __float2bfloat16(vv[1]),
                 __float2bfloat16(vv[2]), __float2bfloat16(vv[3]) };
  *(uint2*)(x + (size_t)row * 256 + lane * 4) = *(uint2*)xo;
  float4 a4 = *(const float4*)(na + lane * 4);
  float4 b4 = *(const float4*)(nb + lane * 4);
  bf16 o4[4] = { __float2bfloat16(a4.x * d0 * inv + b4.x),
                 __float2bfloat16(a4.y * d1 * inv + b4.y),
                 __float2bfloat16(a4.z * d2 * inv + b4.z),
                 __float2bfloat16(a4.w * d3 * inv + b4.w) };
  *(uint2*)(xn + (size_t)row * 256 + lane * 4) = *(uint2*)o4;
}

// LN over bf16 x -> bf16 xn. one wave per row. grid 23040.
__global__ __launch_bounds__(256) void ln_k(
    const bf16* __restrict__ x, const float* __restrict__ na,
    const float* __restrict__ nb, bf16* __restrict__ xn)
{
  int row  = blockIdx.x * 4 + (threadIdx.x >> 6);
  int lane = threadIdx.x & 63;
  uint2 raw = *(const uint2*)(x + (size_t)row * 256 + lane * 4);
  bf16* xr = (bf16*)&raw;
  float v0 = __bfloat162float(xr[0]), v1 = __bfloat162float(xr[1]);
  float v2 = __bfloat162float(xr[2]), v3 = __bfloat162float(xr[3]);
  float sum = wave_sum64(v0 + v1 + v2 + v3);
  float mu = sum * (1.0f / 256.0f);
  float d0 = v0-mu, d1 = v1-mu, d2 = v2-mu, d3 = v3-mu;
  float sq = wave_sum64(d0*d0 + d1*d1 + d2*d2 + d3*d3);
  float inv = 1.0f / (sqrtf(sq * (1.0f / 255.0f)) + 1e-6f);
  float4 a4 = *(const float4*)(na + lane * 4);
  float4 b4 = *(const float4*)(nb + lane * 4);
  bf16 o4[4] = { __float2bfloat16(a4.x * d0 * inv + b4.x),
                 __float2bfloat16(a4.y * d1 * inv + b4.y),
                 __float2bfloat16(a4.z * d2 * inv + b4.z),
                 __float2bfloat16(a4.w * d3 * inv + b4.w) };
  *(uint2*)(xn + (size_t)row * 256 + lane * 4) = *(uint2*)o4;
}

// C = A[M][K] @ Bt[N][K]^T + bias. 128x128 tile, BK=32, global_load_lds staging.
// MODE 2: relu, bf16 row-major [M][N]
// MODE 3: bf16 residual in-place: xres[m*256+n] += acc (+bias)
// MODE 4: merged QKV epilogue (N=768): n<256 q-layout, <512 k-layout, else v^T
template<int MODE>
__global__ __launch_bounds__(256) void gemm_bt(
    const bf16* __restrict__ A, int lda,
    const bf16* __restrict__ Bt, int ldb,
    const float* __restrict__ bias,      // MODE2/3 bias (or null)
    bf16* __restrict__ outb, bf16* __restrict__ xres,
    int N, int K,
    const float* __restrict__ bq, const float* __restrict__ bk,
    const float* __restrict__ bv)
{
  __shared__ bf16 As[128 * 32];
  __shared__ bf16 Bs[128 * 32];
  int m0 = blockIdx.x * 128, n0 = blockIdx.y * 128;
  int tid = threadIdx.x;
  int wave = tid >> 6, lane = tid & 63;
  int wm = (wave >> 1) * 64, wn = (wave & 1) * 64;
  int r = lane & 15, qd = lane >> 4;

  // staging: slot = wave*128 + t*64 + lane; row = slot>>2, c = slot&3
  int slot0 = wave * 128 + lane;
  int row0 = slot0 >> 2, c0 = slot0 & 3;
  int row1 = (slot0 + 64) >> 2, c1 = (slot0 + 64) & 3;
  const bf16* ag0 = A  + (size_t)(m0 + row0) * lda + c0 * 8;
  const bf16* ag1 = A  + (size_t)(m0 + row1) * lda + c1 * 8;
  const bf16* bg0 = Bt + (size_t)(n0 + row0) * ldb + c0 * 8;
  const bf16* bg1 = Bt + (size_t)(n0 + row1) * ldb + c1 * 8;
  bf16* lA0 = As + (size_t)(wave * 128) * 8;
  bf16* lA1 = As + (size_t)(wave * 128 + 64) * 8;
  bf16* lB0 = Bs + (size_t)(wave * 128) * 8;
  bf16* lB1 = Bs + (size_t)(wave * 128 + 64) * 8;

  f32x4 acc[4][4];
  #pragma unroll
  for (int mt = 0; mt < 4; mt++)
    #pragma unroll
    for (int nt = 0; nt < 4; nt++) acc[mt][nt] = (f32x4){0.f, 0.f, 0.f, 0.f};

  for (int k0 = 0; k0 < K; k0 += 32){
    gl_lds16(ag0, lA0); gl_lds16(ag1, lA1);
    gl_lds16(bg0, lB0); gl_lds16(bg1, lB1);
    ag0 += 32; ag1 += 32; bg0 += 32; bg1 += 32;
    __syncthreads();           // drains vmcnt (compiler-inserted) + barrier
    frag8 af[4], bfr[4];
    #pragma unroll
    for (int t = 0; t < 4; t++){
      af[t]  = *(const frag8*)(As + (wm + t * 16 + r) * 32 + qd * 8);
      bfr[t] = *(const frag8*)(Bs + (wn + t * 16 + r) * 32 + qd * 8);
    }
    #pragma unroll
    for (int mt = 0; mt < 4; mt++)
      #pragma unroll
      for (int nt = 0; nt < 4; nt++)
        acc[mt][nt] = __builtin_amdgcn_mfma_f32_16x16x32_bf16(af[mt], bfr[nt], acc[mt][nt], 0, 0, 0);
    __syncthreads();           // WAR: next staging vs this iter's reads
  }

  #pragma unroll
  for (int mt = 0; mt < 4; mt++)
    #pragma unroll
    for (int nt = 0; nt < 4; nt++)
      #pragma unroll
      for (int i = 0; i < 4; i++){
        int m = m0 + wm + mt * 16 + qd * 4 + i;
        int n = n0 + wn + nt * 16 + r;
        float v = acc[mt][nt][i];
        if (MODE == 2){
          v += bias[n];
          v = fmaxf(v, 0.0f);
          outb[(size_t)m * N + n] = __float2bfloat16(v);
        } else if (MODE == 3){
          if (bias) v += bias[n];
          size_t o = (size_t)m * 256 + n;
          xres[o] = __float2bfloat16(__bfloat162float(xres[o]) + v);
        } else {  // MODE 4
          int region = n >> 8, nn = n & 255;
          int h = nn >> 6, dk = nn & 63;
          v += (region == 0 ? bq : region == 1 ? bk : bv)[nn];
          int b = m / 360, s = m - b * 360;
          if (region < 2){
            size_t off = (((size_t)(b * 4 + h) * 360 + s) << 6) + dk;
            outb[off + (size_t)region * 11796480] = __float2bfloat16(v);
          } else {
            outb[23592960 + ((size_t)((b * 4 + h) * 64 + dk)) * 360 + s] = __float2bfloat16(v);
          }
        }
      }
}

// streaming 2-pass attention. grid (6, 512): blockIdx.y = (b_local,h),
// blockIdx.x*4+wave = q-tile (0..22; 23 idles). No __syncthreads anywhere.
__global__ __launch_bounds__(256) void attn2(
    const bf16* __restrict__ q, const bf16* __restrict__ kk, const bf16* __restrict__ vt,
    const int* __restrict__ src, bf16* __restrict__ ctx)
{
  __shared__ bf16 P[4][16][48];   // per-wave 16x48 (stride 48: 16B-aligned reads)
  int bh = blockIdx.y;
  int b = bh >> 2, h = bh & 3;
  int wave = threadIdx.x >> 6, lane = threadIdx.x & 63;
  int qt = blockIdx.x * 4 + wave;
  if (qt >= 23) return;
  int r = lane & 15, qd = lane >> 4;
  const bf16* qb = q  + (size_t)bh * 360 * 64;
  const bf16* kb = kk + (size_t)bh * 360 * 64;
  const bf16* vb = vt + (size_t)bh * 64 * 360;
  bf16 (* __restrict__ Pw)[48] = P[wave];
  const int* srow = src + b * 360;

  int qg = qt * 16 + r;                 // this lane's query (as MFMA col n)
  int qrow = qg > 359 ? 359 : qg;
  frag8 qa0 = *(const frag8*)(qb + qrow * 64 + qd * 8);
  frag8 qa1 = *(const frag8*)(qb + qrow * 64 + 32 + qd * 8);
  bool qp = (qg < 360) && (srow[qg] == 799);   // reference masks PAD queries

  // ---- pass 1: row max (scores streamed, nothing stored) ----
  float mrun = -INFINITY;
  for (int kt = 0; kt < 23; kt++){
    int krow = kt * 16 + r; if (krow > 359) krow = 359;
    frag8 kf0 = *(const frag8*)(kb + krow * 64 + qd * 8);
    frag8 kf1 = *(const frag8*)(kb + krow * 64 + 32 + qd * 8);
    f32x4 z = {0.f, 0.f, 0.f, 0.f};
    z = __builtin_amdgcn_mfma_f32_16x16x32_bf16(kf0, qa0, z, 0, 0, 0);   // C[key][query]
    z = __builtin_amdgcn_mfma_f32_16x16x32_bf16(kf1, qa1, z, 0, 0, 0);
    #pragma unroll
    for (int i = 0; i < 4; i++){
      int key = kt * 16 + qd * 4 + i;
      float s = z[i] * 0.125f;
      if (qp) s = -1.0e9f;
      if (key >= 360) s = -INFINITY;
      mrun = fmaxf(mrun, s);
    }
  }
  mrun = fmaxf(mrun, __shfl_xor(mrun, 16, 64));
  mrun = fmaxf(mrun, __shfl_xor(mrun, 32, 64));   // max for query qg (all quads)

  // ---- pass 2: recompute, exp, P->LDS(A-frag), PV ----
  float lsum = 0.f;
  f32x4 accO[4];
  #pragma unroll
  for (int dt = 0; dt < 4; dt++) accO[dt] = (f32x4){0.f, 0.f, 0.f, 0.f};

  for (int kc = 0; kc < 12; kc++){
    #pragma unroll
    for (int hf = 0; hf < 2; hf++){
      int kt = kc * 2 + hf;                       // kt=23: all keys masked -> p=0
      int krow = kt * 16 + r; if (krow > 359) krow = 359;
      frag8 kf0 = *(const frag8*)(kb + krow * 64 + qd * 8);
      frag8 kf1 = *(const frag8*)(kb + krow * 64 + 32 + qd * 8);
      f32x4 z = {0.f, 0.f, 0.f, 0.f};
      z = __builtin_amdgcn_mfma_f32_16x16x32_bf16(kf0, qa0, z, 0, 0, 0);
      z = __builtin_amdgcn_mfma_f32_16x16x32_bf16(kf1, qa1, z, 0, 0, 0);
      float p[4];
      #pragma unroll
      for (int i = 0; i < 4; i++){
        int key = kt * 16 + qd * 4 + i;
        float s = z[i] * 0.125f;
        if (qp) s = -1.0e9f;
        float pv = (key < 360) ? __expf(s - mrun) : 0.0f;
        p[i] = pv;
        lsum += pv;
      }
      // lane (qd,r) holds P[query=r][keys kt*16+qd*4..+3] -> Pw[r][hf*16+qd*4]
      *(uint2*)(&Pw[r][hf * 16 + qd * 4]) = make_uint2(pack2(p[0], p[1]), pack2(p[2], p[3]));
    }
    asm volatile("s_waitcnt lgkmcnt(0)" ::: "memory");   // cross-lane write->read
    frag8 pa = *(const frag8*)(&Pw[r][qd * 8]);          // A[m=query][k=key32]
    #pragma unroll
    for (int dt = 0; dt < 4; dt++){
      frag8 vf = *(const frag8*)(vb + (size_t)(dt * 16 + r) * 360 + kc * 32 + qd * 8);
      accO[dt] = __builtin_amdgcn_mfma_f32_16x16x32_bf16(pa, vf, accO[dt], 0, 0, 0);
    }
  }

  lsum += __shfl_xor(lsum, 16, 64);
  lsum += __shfl_xor(lsum, 32, 64);
  float invl = 1.0f / lsum;                       // for query qg
  #pragma unroll
  for (int i = 0; i < 4; i++){
    float inv_i = __shfl(invl, qd * 4 + i, 64);   // invl of query qt*16+qd*4+i
    int qglob = qt * 16 + qd * 4 + i;
    if (qglob < 360){
      #pragma unroll
      for (int dt = 0; dt < 4; dt++)
        ctx[((size_t)(b * 360 + qglob)) * 256 + h * 64 + dt * 16 + r] =
            __float2bfloat16(accO[dt][i] * inv_i);
    }
  }
}

// head: one wave per (b, pair). 5824 blocks x 4 waves = 23296 = 256*91.
__global__ __launch_bounds__(256) void head_k(
    const bf16* __restrict__ x, const int* __restrict__ src,
    const float* __restrict__ wl, const float* __restrict__ bl,
    float* __restrict__ out)
{
  int widx = blockIdx.x * 4 + (threadIdx.x >> 6);
  if (widx >= 23296) return;
  int lane = threadIdx.x & 63;
  int b = widx / 91, p = widx - b * 91;

  int i = 0, rem = p;
  while (rem >= 13 - i){ rem -= 13 - i; i++; }
  int j = i + 1 + rem;
  int base = 12 * i - (i * (i - 1)) / 2;
  int pe = base + (j - i) - 1;
  int eb = 28 + 2 * pe;

  int g = lane >> 3, sub = lane & 7;
  int idxg;
  if (g == 0) idxg = 2 * i;
  else if (g == 1) idxg = 2 * i + 1;
  else if (g == 2) idxg = 2 * j;
  else if (g == 3) idxg = 2 * j + 1;
  else idxg = eb + (g - 4);
  bool zm = !(g >= 4 && j == 13);

  float a0 = 0.f, a1 = 0.f, a2 = 0.f;
  if (zm){
    const bf16* xr = x + ((size_t)b * 360 + idxg) * 256 + sub * 32;
    const float* wr = wl + (size_t)(g * 256 + sub * 32) * 3;
    #pragma unroll
    for (int t = 0; t < 32; t++){
      float f = __bfloat162float(xr[t]);
      a0 += f * wr[t * 3 + 0];
      a1 += f * wr[t * 3 + 1];
      a2 += f * wr[t * 3 + 2];
    }
  }
  #pragma unroll
  for (int o = 1; o < 64; o <<= 1){
    a0 += __shfl_xor(a0, o, 64);
    a1 += __shfl_xor(a1, o, 64);
    a2 += __shfl_xor(a2, o, 64);
  }
  if (lane == 0){
    const int* sr = src + b * 360;
    int ti = sr[2 * i], ai = sr[2 * i + 1], tj = sr[2 * j], aj = sr[2 * j + 1];
    bool c1 = (ai == 2) || (aj == 2);
    bool c2 = (tj == 1) || (ai == 1) || (aj == 1);
    bool c3 = (ti == 799) || (tj == 799) || (ai == 0) || (aj == 0);
    bool c4 = false;
    if (j < 13){
      int es = 28 + 4 * pe;
      c4 = (sr[es] == 1) || (sr[es + 1] == 1) || (sr[es + 2] == 1) || (sr[es + 3] == 1);
    }
    bool m1 = c3 || c4, m2 = m1 || c2, m3 = m2 || c1;
    float* op = out + ((size_t)b * 91 + p) * 3;
    op[0] = m1 ? -1.0e9f : (a0 + bl[0]);
    op[1] = m2 ? -1.0e9f : (a1 + bl[1]);
    op[2] = m3 ? -1.0e9f : (a2 + bl[2]);
  }
}

extern "C" void kernel_launch(void* const* d_in, const int* in_sizes, int n_in,
                              void* d_out, int out_size, void* d_ws, size_t ws_size,
                              hipStream_t stream)
{
  const int*   src = (const int*)  d_in[0];
  const float* emb = (const float*)d_in[1];
  const float* wq  = (const float*)d_in[2];  const float* bq = (const float*)d_in[3];
  const float* wk  = (const float*)d_in[4];  const float* bk = (const float*)d_in[5];
  const float* wv  = (const float*)d_in[6];  const float* bv = (const float*)d_in[7];
  const float* wo  = (const float*)d_in[8];  const float* bo = (const float*)d_in[9];
  const float* n1a = (const float*)d_in[10]; const float* n1b = (const float*)d_in[11];
  const float* n2a = (const float*)d_in[12]; const float* n2b = (const float*)d_in[13];
  const float* w1  = (const float*)d_in[14]; const float* b1 = (const float*)d_in[15];
  const float* w2  = (const float*)d_in[16]; const float* b2 = (const float*)d_in[17];
  const float* wl  = (const float*)d_in[18]; const float* bl = (const float*)d_in[19];
  float* out = (float*)d_out;

  if (ws_size < 191365120ull) return;

  char* ws = (char*)d_ws;
  bf16* x   = (bf16*)(ws);                    // [92160][256]
  bf16* xn  = (bf16*)(ws + 47185920ull);      // [92160][256]
  char* R   = ws + 94371840ull;
  bf16* qh   = (bf16*)(R);                    // [512][360][64]; k at +11796480 el, v^T at +23592960 el
  bf16* kh   = (bf16*)(R + 23592960ull);
  bf16* vth  = (bf16*)(R + 47185920ull);      // [512][64][360]
  bf16* ctxh = (bf16*)(R + 70778880ull);      // [46080][256]
  bf16* hbuf = (bf16*)(R);                    // ffn phase: [92160][512]
  bf16* wT   = (bf16*)(ws + 188743680ull);
  bf16* wqT = wT;                // rows 0..255 of merged [768][256]
  bf16* wkT = wT + 65536;
  bf16* wvT = wT + 131072;
  bf16* woT = wT + 196608;
  bf16* w1T = wT + 262144;       // [2048][256]
  bf16* w2T = w1T + 524288;      // [256][2048]

  cvt_transpose<<<256, 256, 0, stream>>>(wqT, wq, 256, 256);
  cvt_transpose<<<256, 256, 0, stream>>>(wkT, wk, 256, 256);
  cvt_transpose<<<256, 256, 0, stream>>>(wvT, wv, 256, 256);
  cvt_transpose<<<256, 256, 0, stream>>>(woT, wo, 256, 256);
  cvt_transpose<<<2048, 256, 0, stream>>>(w1T, w1, 256, 2048);
  cvt_transpose<<<2048, 256, 0, stream>>>(w2T, w2, 2048, 256);

  embed_ln1<<<23040, 256, 0, stream>>>(src, emb, n1a, n1b, x, xn);

  dim3 gqkv(360, 6), gh(360, 2), g2(720, 2), g4(720, 4);
  for (int half = 0; half < 2; half++){
    size_t ro = (size_t)half * 46080;
    const bf16* xnh = xn + ro * 256;
    gemm_bt<4><<<gqkv, 256, 0, stream>>>(xnh, 256, wqT, 256, nullptr, qh, nullptr,
                                         768, 256, bq, bk, bv);
    attn2<<<dim3(6, 512), 256, 0, stream>>>(qh, kh, vth, src + ro, ctxh);
    gemm_bt<3><<<gh, 256, 0, stream>>>(ctxh, 256, woT, 256, bo, nullptr, x + ro * 256,
                                       256, 256, nullptr, nullptr, nullptr);
  }

  ln_k<<<23040, 256, 0, stream>>>(x, n2a, n2b, xn);

  for (int c = 0; c < 4; c++){
    gemm_bt<2><<<g4, 256, 0, stream>>>(xn, 256, w1T + (size_t)c * 512 * 256, 256,
                                       b1 + c * 512, hbuf, nullptr, 512, 256,
                                       nullptr, nullptr, nullptr);
    gemm_bt<3><<<g2, 256, 0, stream>>>(hbuf, 512, w2T + (size_t)c * 512, 2048,
                                       (c == 0 ? b2 : nullptr), nullptr, x, 256, 512,
                                       nullptr, nullptr, nullptr);
  }

  head_k<<<5824, 256, 0, stream>>>(x, src, wl, bl, out);
}